// Round 9
// baseline (188.696 us; speedup 1.0000x reference)
//
#include <hip/hip_runtime.h>
#include <hip/hip_bf16.h>

typedef short short8 __attribute__((ext_vector_type(8)));
typedef short short4v __attribute__((ext_vector_type(4)));
typedef float f32x4 __attribute__((ext_vector_type(4)));

#define E 256
#define DH 128

__device__ __forceinline__ float bf2f(__hip_bfloat16 x) { return __bfloat162float(x); }
__device__ __forceinline__ __hip_bfloat16 f2bf(float x) { return __float2bfloat16(x); }

// ---------- fused fp32 -> bf16 convert for 6 arrays ----------
struct CvtArgs { const float* in[6]; __hip_bfloat16* out[6]; int n[6]; };

__global__ __launch_bounds__(256) void f2b_all(CvtArgs a)
{
    int seg = blockIdx.y;
    int i = (blockIdx.x * 256 + threadIdx.x) * 8;
    if (i >= a.n[seg]) return;
    const float* in = a.in[seg];
    float4 x = *reinterpret_cast<const float4*>(in + i);
    float4 y = *reinterpret_cast<const float4*>(in + i + 4);
    __hip_bfloat16* o = a.out[seg] + i;
    o[0] = f2bf(x.x); o[1] = f2bf(x.y); o[2] = f2bf(x.z); o[3] = f2bf(x.w);
    o[4] = f2bf(y.x); o[5] = f2bf(y.y); o[6] = f2bf(y.z); o[7] = f2bf(y.w);
}

// ---------- projection GEMM: out[M,256] = A[M,256] @ W[256,256]^T + b ----------
// LDS-staged 2-phase pipeline (global_load_lds width=16), VERBATIM from Round 5
// (the 179->169 win): DMA-queued staging at zero VGPR cost; W-slab shared per
// block; XOR swizzle applied both-sides (pre-swizzled source + swizzled read).
struct ProjSeg { const __hip_bfloat16* A; const __hip_bfloat16* W; const float* b; __hip_bfloat16* out; };
struct ProjArgs { ProjSeg seg[5]; };

#define GLDS(g, l) __builtin_amdgcn_global_load_lds( \
    (const __attribute__((address_space(1))) void*)(g), \
    (__attribute__((address_space(3))) void*)(l), 16, 0, 0)

__global__ __launch_bounds__(256) void gemm_proj(ProjArgs args, int M)
{
    __shared__ __hip_bfloat16 sA[2][32 * 64];    //  8 KB: A slab, 32 rows x 64 k
    __shared__ __hip_bfloat16 sW[2][256 * 64];   // 64 KB: W slab, 256 rows x 64 k

    int wv = threadIdx.x >> 6, lane = threadIdx.x & 63;
    int m0 = blockIdx.x * 32;
    ProjSeg sg = args.seg[blockIdx.y];
    int lo = lane & 15, hi = lane >> 4;

    int lr = lane >> 3;                        // row within 8-row group == row&7
    int lcol = ((lane & 7) ^ lr) * 8;          // pre-swizzled source col (elements)

    auto stage = [&](int buf, int kc) {
        {   // A: instr index = wv, rows wv*8 .. wv*8+8
            int R = wv * 8 + lr;
            GLDS(sg.A + (size_t)(m0 + R) * E + kc * 64 + lcol, &sA[buf][(wv * 8) * 64]);
        }
#pragma unroll
        for (int s = 0; s < 8; ++s) {   // W: instrs wv*8+s, rows wv*64+s*8 ..+8
            int R = wv * 64 + s * 8 + lr;
            GLDS(sg.W + (size_t)R * E + kc * 64 + lcol, &sW[buf][(wv * 64 + s * 8) * 64]);
        }
    };

    stage(0, 0);
    __syncthreads();                            // drain vmcnt(0): buf0 ready

    f32x4 acc[2][4] = {};
    const int swz = (lo & 7);                   // read-side swizzle term (row&7)
#pragma unroll
    for (int kc = 0; kc < 4; ++kc) {
        int cur = kc & 1;
        if (kc < 3) stage(cur ^ 1, kc + 1);     // DMA flies under this chunk's math

        const char* aB = (const char*)sA[cur];
        const char* wB = (const char*)sW[cur];
#pragma unroll
        for (int ks = 0; ks < 2; ++ks) {
            int phys = ((hi + 4 * ks) ^ swz) * 16;   // swizzled 16B slot in row
            short8 a0 = *reinterpret_cast<const short8*>(aB + (0 * 16 + lo) * 128 + phys);
            short8 a1 = *reinterpret_cast<const short8*>(aB + (1 * 16 + lo) * 128 + phys);
#pragma unroll
            for (int nt = 0; nt < 4; ++nt) {
                short8 b = *reinterpret_cast<const short8*>(
                    wB + (wv * 64 + nt * 16 + lo) * 128 + phys);
                acc[0][nt] = __builtin_amdgcn_mfma_f32_16x16x32_bf16(a0, b, acc[0][nt], 0, 0, 0);
                acc[1][nt] = __builtin_amdgcn_mfma_f32_16x16x32_bf16(a1, b, acc[1][nt], 0, 0, 0);
            }
        }
        __syncthreads();    // drains vmcnt(0): next buf staged; all reads of cur done
    }

#pragma unroll
    for (int nt = 0; nt < 4; ++nt) {
        int col = wv * 64 + nt * 16 + lo;
        float bias = sg.b[col];
#pragma unroll
        for (int mt = 0; mt < 2; ++mt)
#pragma unroll
            for (int r = 0; r < 4; ++r) {
                int row = m0 + mt * 16 + hi * 4 + r;
                sg.out[(size_t)row * E + col] = f2bf(acc[mt][nt][r] + bias);
            }
    }
}

// ---------- fused: sparse attn -> LDS -> outproj MFMA -> +resid -> LN (-> Q-next proj) ----------
// R8-verified per-wave code; geometry changed 16 waves -> 8 waves per block
// (512 thr, grid L/8 = 1024): 4 blocks/CU resident instead of 2 -> 2x phase
// diversity against the measured latency-bound profile (VALUBusy 22%, MfmaUtil
// 1.9%, 2-block barrier convoys). MFMA phases keep the 16-row A-tile; rows 8..15
// are ZEROED once at kernel top (zero A-rows -> zero D-rows, store-guarded away;
// numerically exact -- R7's uninitialized-garbage suspect eliminated). Each wave
// now covers 32 output cols via nt=0,1; stores guarded hi<2 (rows 0..7).
__global__ __launch_bounds__(512) void attn_outproj_ln(
    const int* __restrict__ rel, const __hip_bfloat16* __restrict__ q16,
    const __hip_bfloat16* __restrict__ k16, const __hip_bfloat16* __restrict__ v16,
    const __hip_bfloat16* __restrict__ wout, const float* __restrict__ bout,
    const float* __restrict__ resid, const float* __restrict__ lng, const float* __restrict__ lnb,
    const __hip_bfloat16* __restrict__ wq_next, const float* __restrict__ bq_next,
    float* __restrict__ xres_out, __hip_bfloat16* __restrict__ qnext_out,
    float* __restrict__ final_out, int L, int ML)
{
    __shared__ __align__(16) __hip_bfloat16 atile[16 * 264];  // rows 0..7 live, 8..15 zero
    __shared__ __align__(16) float sm[8 * 260];
    __shared__ __align__(16) float lds_w[8][2][16];
    __shared__ int lds_idx[8][16];

    int tid = threadIdx.x, wv = tid >> 6, lane = tid & 63;
    int m0 = blockIdx.x * 8;
    int g = lane >> 2, q = lane & 3;
    int face = m0 + wv;
    const float scale = 0.088388347648318447f;  // 1/sqrt(128)

    // ---- zero the dead A-tile rows (8..15); persists through both MFMA phases
    {
        short4v z = {0, 0, 0, 0};
        *reinterpret_cast<short4v*>(atile + (wv + 8) * 264 + 4 * lane) = z;
    }

    // ---- hoisted cold reads: rel (gather indices) + resid row ----
    const int* rr = rel + (size_t)face * ML;
    int myidx = (g < ML) ? rr[g] : -1;
    float4 rv = *reinterpret_cast<const float4*>(resid + (size_t)face * E + 4 * lane);

    bool dup = false;
#pragma unroll
    for (int d = 1; d < 16; ++d) {
        int other = __shfl(myidx, ((g - d) & 15) * 4 + q);
        if (d <= g && other == myidx) dup = true;
    }
    bool myuse = (myidx >= 0) && !dup;       // set semantics: unique valid edges
    int safe = myidx < 0 ? 0 : myidx;
    if (q == 0) lds_idx[wv][g] = safe;

    // ---- QK dots (per-head, loads kept in-loop to cap liveness) ----
    float sc[2];
#pragma unroll
    for (int h = 0; h < 2; ++h) {
        const __hip_bfloat16* kbase = k16 + (size_t)safe * E + h * DH;
        const __hip_bfloat16* qbase = q16 + (size_t)face * E + h * DH;
        float part = 0.f;
#pragma unroll
        for (int t = 0; t < 4; ++t) {
            short8 qv = *reinterpret_cast<const short8*>(qbase + (t * 4 + q) * 8);
            short8 kv = *reinterpret_cast<const short8*>(kbase + (t * 4 + q) * 8);
            const __hip_bfloat16* qp = (const __hip_bfloat16*)&qv;
            const __hip_bfloat16* kp = (const __hip_bfloat16*)&kv;
#pragma unroll
            for (int e2 = 0; e2 < 8; ++e2)
                part += bf2f(qp[e2]) * bf2f(kp[e2]);
        }
        part += __shfl_xor(part, 1);
        part += __shfl_xor(part, 2);          // full 128-dim dot in all 4 quad lanes
        sc[h] = myuse ? part * scale : -1e30f;
    }
    // interleaved softmax reductions for both heads (2x ILP, identical values)
    {
        float mx0 = sc[0], mx1 = sc[1];
#pragma unroll
        for (int off = 4; off < 64; off <<= 1) {
            mx0 = fmaxf(mx0, __shfl_xor(mx0, off));
            mx1 = fmaxf(mx1, __shfl_xor(mx1, off));
        }
        float e0 = __expf(sc[0] - mx0), e1 = __expf(sc[1] - mx1);  // exactly 0 for dead slots
        float d0 = e0, d1 = e1;
#pragma unroll
        for (int off = 4; off < 64; off <<= 1) {
            d0 += __shfl_xor(d0, off);
            d1 += __shfl_xor(d1, off);
        }
        if (q == 0) { lds_w[wv][0][g] = e0 / d0; lds_w[wv][1][g] = e1 / d1; }
    }

    // V phase: lane covers dims [4*lane, 4*lane+4) of the 256-dim row
    {
        int h = lane >> 5;
        float a0 = 0.f, a1 = 0.f, a2 = 0.f, a3 = 0.f;
#pragma unroll
        for (int j = 0; j < 16; ++j) {
            int ij = lds_idx[wv][j];
            float wj = lds_w[wv][h][j];       // 0 for unused edges
            short4v vv = *reinterpret_cast<const short4v*>(v16 + (size_t)ij * E + 4 * lane);
            const __hip_bfloat16* vp = (const __hip_bfloat16*)&vv;
            a0 += wj * bf2f(vp[0]);
            a1 += wj * bf2f(vp[1]);
            a2 += wj * bf2f(vp[2]);
            a3 += wj * bf2f(vp[3]);
        }
        __hip_bfloat16 ob[4] = {f2bf(a0), f2bf(a1), f2bf(a2), f2bf(a3)};
        *reinterpret_cast<short4v*>(atile + wv * 264 + 4 * lane) =
            *reinterpret_cast<const short4v*>(ob);
    }
    __syncthreads();

    // ---- outproj MFMA: wave wv -> cols [wv*32, wv*32+32); A rows 8..15 zero ----
    {
        int lo = lane & 15, hi = lane >> 4;
        const __hip_bfloat16* arow = atile + lo * 264 + hi * 8;
        f32x4 acc[2] = {};
#pragma unroll
        for (int nt = 0; nt < 2; ++nt) {
            const __hip_bfloat16* brow = wout + (size_t)(wv * 32 + nt * 16 + lo) * E + hi * 8;
#pragma unroll
            for (int kk = 0; kk < 8; ++kk) {
                short8 a = *reinterpret_cast<const short8*>(arow + kk * 32);
                short8 b = *reinterpret_cast<const short8*>(brow + kk * 32);
                acc[nt] = __builtin_amdgcn_mfma_f32_16x16x32_bf16(a, b, acc[nt], 0, 0, 0);
            }
        }
        if (hi < 2) {   // rows hi*4+r = 0..7 are the real faces
#pragma unroll
            for (int nt = 0; nt < 2; ++nt) {
                int col = wv * 32 + nt * 16 + lo;
#pragma unroll
                for (int r = 0; r < 4; ++r)
                    sm[(hi * 4 + r) * 260 + col] = acc[nt][r];
            }
        }
    }
    __syncthreads();

    // ---- LN: wave wv handles row wv; lane covers 4 cols (rv preloaded) ----
    {
        int rowg = m0 + wv;
        float4 pv = *reinterpret_cast<const float4*>(sm + wv * 260 + 4 * lane);
        float4 bb = *reinterpret_cast<const float4*>(bout + 4 * lane);
        float v0 = pv.x + bb.x + rv.x;
        float v1 = pv.y + bb.y + rv.y;
        float v2 = pv.z + bb.z + rv.z;
        float v3 = pv.w + bb.w + rv.w;
        float s  = v0 + v1 + v2 + v3;
        float s2 = v0 * v0 + v1 * v1 + v2 * v2 + v3 * v3;
#pragma unroll
        for (int off = 1; off < 64; off <<= 1) {
            s  += __shfl_xor(s, off);
            s2 += __shfl_xor(s2, off);
        }
        float mean = s * (1.f / 256.f);
        float var  = s2 * (1.f / 256.f) - mean * mean;
        float rstd = rsqrtf(var + 1e-5f);
        float4 gg = *reinterpret_cast<const float4*>(lng + 4 * lane);
        float4 b2 = *reinterpret_cast<const float4*>(lnb + 4 * lane);
        float y0 = (v0 - mean) * rstd * gg.x + b2.x;
        float y1 = (v1 - mean) * rstd * gg.y + b2.y;
        float y2 = (v2 - mean) * rstd * gg.z + b2.z;
        float y3 = (v3 - mean) * rstd * gg.w + b2.w;
        if (final_out) {
            float4 o = {y0, y1, y2, y3};
            *reinterpret_cast<float4*>(final_out + (size_t)rowg * E + 4 * lane) = o;  // fp32 d_out
        } else {
            float4 o = {y0, y1, y2, y3};
            *reinterpret_cast<float4*>(xres_out + (size_t)rowg * E + 4 * lane) = o;
            // stage LN output as bf16 for the fused Q-next projection
            __hip_bfloat16 ob[4] = {f2bf(y0), f2bf(y1), f2bf(y2), f2bf(y3)};
            *reinterpret_cast<short4v*>(atile + wv * 264 + 4 * lane) =
                *reinterpret_cast<const short4v*>(ob);
        }
    }

    // ---- fused Q-next projection (layer 0 only): q16[m0..m0+7] = y @ wq^T + bq ----
    if (qnext_out) {
        __syncthreads();   // atile(y) visible to all waves; rows 8..15 still zero
        int lo = lane & 15, hi = lane >> 4;
        const __hip_bfloat16* arow = atile + lo * 264 + hi * 8;
        f32x4 acc[2] = {};
#pragma unroll
        for (int nt = 0; nt < 2; ++nt) {
            const __hip_bfloat16* brow = wq_next + (size_t)(wv * 32 + nt * 16 + lo) * E + hi * 8;
#pragma unroll
            for (int kk = 0; kk < 8; ++kk) {
                short8 a = *reinterpret_cast<const short8*>(arow + kk * 32);
                short8 b = *reinterpret_cast<const short8*>(brow + kk * 32);
                acc[nt] = __builtin_amdgcn_mfma_f32_16x16x32_bf16(a, b, acc[nt], 0, 0, 0);
            }
        }
        if (hi < 2) {
#pragma unroll
            for (int nt = 0; nt < 2; ++nt) {
                int col = wv * 32 + nt * 16 + lo;
                float bias = bq_next[col];
#pragma unroll
                for (int r = 0; r < 4; ++r)
                    qnext_out[(size_t)(m0 + hi * 4 + r) * E + col] = f2bf(acc[nt][r] + bias);
            }
        }
    }
}

extern "C" void kernel_launch(void* const* d_in, const int* in_sizes, int n_in,
                              void* d_out, int out_size, void* d_ws, size_t ws_size,
                              hipStream_t stream) {
    const int* rel = (const int*)d_in[0];
    const float* edge = (const float*)d_in[2];
    const float* face = (const float*)d_in[3];
    const float* w_in[2]  = {(const float*)d_in[4],  (const float*)d_in[10]};
    const float* b_in[2]  = {(const float*)d_in[5],  (const float*)d_in[11]};
    const float* w_out[2] = {(const float*)d_in[6],  (const float*)d_in[12]};
    const float* b_out[2] = {(const float*)d_in[7],  (const float*)d_in[13]};
    const float* ln_g[2]  = {(const float*)d_in[8],  (const float*)d_in[14]};
    const float* ln_b[2]  = {(const float*)d_in[9],  (const float*)d_in[15]};

    int S = in_sizes[2] / E;
    int L = in_sizes[3] / E;
    int ML = in_sizes[0] / L;

    char* ws = (char*)d_ws;
    __hip_bfloat16* face16 = (__hip_bfloat16*)ws; ws += (size_t)L * E * 2;
    __hip_bfloat16* edge16 = (__hip_bfloat16*)ws; ws += (size_t)S * E * 2;
    __hip_bfloat16* q16    = (__hip_bfloat16*)ws; ws += (size_t)L * E * 2;
    __hip_bfloat16* k16[2], *v16[2];
    for (int l = 0; l < 2; ++l) {
        k16[l] = (__hip_bfloat16*)ws; ws += (size_t)S * E * 2;
        v16[l] = (__hip_bfloat16*)ws; ws += (size_t)S * E * 2;
    }
    float* xres = (float*)ws;                     ws += (size_t)L * E * 4;
    __hip_bfloat16* win16[2], *wout16[2];
    for (int l = 0; l < 2; ++l) {
        win16[l]  = (__hip_bfloat16*)ws; ws += (size_t)3 * E * E * 2;
        wout16[l] = (__hip_bfloat16*)ws; ws += (size_t)E * E * 2;
    }

    float* outp = (float*)d_out;

    // 1) conversions (one launch)
    {
        CvtArgs ca;
        ca.in[0] = face;     ca.out[0] = face16;    ca.n[0] = L * E;
        ca.in[1] = edge;     ca.out[1] = edge16;    ca.n[1] = S * E;
        ca.in[2] = w_in[0];  ca.out[2] = win16[0];  ca.n[2] = 3 * E * E;
        ca.in[3] = w_in[1];  ca.out[3] = win16[1];  ca.n[3] = 3 * E * E;
        ca.in[4] = w_out[0]; ca.out[4] = wout16[0]; ca.n[4] = E * E;
        ca.in[5] = w_out[1]; ca.out[5] = wout16[1]; ca.n[5] = E * E;
        int gx = (L * E) / (256 * 8);
        f2b_all<<<dim3(gx, 6), 256, 0, stream>>>(ca);
    }

    // 2) Q0 + K0,V0,K1,V1 projections (one launch, 5 segments, LDS-staged)
    {
        ProjArgs pa;
        pa.seg[0] = {face16, win16[0],                     b_in[0],         q16};
        pa.seg[1] = {edge16, win16[0] + (size_t)E * E,     b_in[0] + E,     k16[0]};
        pa.seg[2] = {edge16, win16[0] + (size_t)2 * E * E, b_in[0] + 2 * E, v16[0]};
        pa.seg[3] = {edge16, win16[1] + (size_t)E * E,     b_in[1] + E,     k16[1]};
        pa.seg[4] = {edge16, win16[1] + (size_t)2 * E * E, b_in[1] + 2 * E, v16[1]};
        gemm_proj<<<dim3(L / 32, 5), 256, 0, stream>>>(pa, L);
    }

    // 3) layer 0: attn + outproj + LN + fused Q1 projection -> xres (f32) + q16 (bf16)
    attn_outproj_ln<<<L / 8, 512, 0, stream>>>(rel, q16, k16[0], v16[0],
                                               wout16[0], b_out[0], face,
                                               ln_g[0], ln_b[0],
                                               win16[1], b_in[1],
                                               xres, q16, nullptr, L, ML);

    // 4) layer 1: attn + outproj + LN -> d_out (f32)
    attn_outproj_ln<<<L / 8, 512, 0, stream>>>(rel, q16, k16[1], v16[1],
                                               wout16[1], b_out[1], xres,
                                               ln_g[1], ln_b[1],
                                               nullptr, nullptr,
                                               nullptr, nullptr, outp, L, ML);
}

// Round 10
// 178.747 us; speedup vs baseline: 1.0557x; 1.0557x over previous
//
#include <hip/hip_runtime.h>
#include <hip/hip_bf16.h>

typedef short short8 __attribute__((ext_vector_type(8)));
typedef short short4v __attribute__((ext_vector_type(4)));
typedef float f32x4 __attribute__((ext_vector_type(4)));

#define E 256
#define DH 128

__device__ __forceinline__ float bf2f(__hip_bfloat16 x) { return __bfloat162float(x); }
__device__ __forceinline__ __hip_bfloat16 f2bf(float x) { return __float2bfloat16(x); }

// ---------- fused fp32 -> bf16 convert for 6 arrays ----------
struct CvtArgs { const float* in[6]; __hip_bfloat16* out[6]; int n[6]; };

__global__ __launch_bounds__(256) void f2b_all(CvtArgs a)
{
    int seg = blockIdx.y;
    int i = (blockIdx.x * 256 + threadIdx.x) * 8;
    if (i >= a.n[seg]) return;
    const float* in = a.in[seg];
    float4 x = *reinterpret_cast<const float4*>(in + i);
    float4 y = *reinterpret_cast<const float4*>(in + i + 4);
    __hip_bfloat16* o = a.out[seg] + i;
    o[0] = f2bf(x.x); o[1] = f2bf(x.y); o[2] = f2bf(x.z); o[3] = f2bf(x.w);
    o[4] = f2bf(y.x); o[5] = f2bf(y.y); o[6] = f2bf(y.z); o[7] = f2bf(y.w);
}

// ---------- projection GEMM: out[M,256] = A[M,256] @ W[256,256]^T + b ----------
// LDS-staged 2-phase pipeline (global_load_lds width=16), VERBATIM from Round 5
// (the 179->169 win): DMA-queued staging at zero VGPR cost; W-slab shared per
// block; XOR swizzle applied both-sides (pre-swizzled source + swizzled read).
struct ProjSeg { const __hip_bfloat16* A; const __hip_bfloat16* W; const float* b; __hip_bfloat16* out; };
struct ProjArgs { ProjSeg seg[5]; };

#define GLDS(g, l) __builtin_amdgcn_global_load_lds( \
    (const __attribute__((address_space(1))) void*)(g), \
    (__attribute__((address_space(3))) void*)(l), 16, 0, 0)

__global__ __launch_bounds__(256) void gemm_proj(ProjArgs args, int M)
{
    __shared__ __hip_bfloat16 sA[2][32 * 64];    //  8 KB: A slab, 32 rows x 64 k
    __shared__ __hip_bfloat16 sW[2][256 * 64];   // 64 KB: W slab, 256 rows x 64 k

    int wv = threadIdx.x >> 6, lane = threadIdx.x & 63;
    int m0 = blockIdx.x * 32;
    ProjSeg sg = args.seg[blockIdx.y];
    int lo = lane & 15, hi = lane >> 4;

    int lr = lane >> 3;                        // row within 8-row group == row&7
    int lcol = ((lane & 7) ^ lr) * 8;          // pre-swizzled source col (elements)

    auto stage = [&](int buf, int kc) {
        {   // A: instr index = wv, rows wv*8 .. wv*8+8
            int R = wv * 8 + lr;
            GLDS(sg.A + (size_t)(m0 + R) * E + kc * 64 + lcol, &sA[buf][(wv * 8) * 64]);
        }
#pragma unroll
        for (int s = 0; s < 8; ++s) {   // W: instrs wv*8+s, rows wv*64+s*8 ..+8
            int R = wv * 64 + s * 8 + lr;
            GLDS(sg.W + (size_t)R * E + kc * 64 + lcol, &sW[buf][(wv * 64 + s * 8) * 64]);
        }
    };

    stage(0, 0);
    __syncthreads();                            // drain vmcnt(0): buf0 ready

    f32x4 acc[2][4] = {};
    const int swz = (lo & 7);                   // read-side swizzle term (row&7)
#pragma unroll
    for (int kc = 0; kc < 4; ++kc) {
        int cur = kc & 1;
        if (kc < 3) stage(cur ^ 1, kc + 1);     // DMA flies under this chunk's math

        const char* aB = (const char*)sA[cur];
        const char* wB = (const char*)sW[cur];
#pragma unroll
        for (int ks = 0; ks < 2; ++ks) {
            int phys = ((hi + 4 * ks) ^ swz) * 16;   // swizzled 16B slot in row
            short8 a0 = *reinterpret_cast<const short8*>(aB + (0 * 16 + lo) * 128 + phys);
            short8 a1 = *reinterpret_cast<const short8*>(aB + (1 * 16 + lo) * 128 + phys);
#pragma unroll
            for (int nt = 0; nt < 4; ++nt) {
                short8 b = *reinterpret_cast<const short8*>(
                    wB + (wv * 64 + nt * 16 + lo) * 128 + phys);
                acc[0][nt] = __builtin_amdgcn_mfma_f32_16x16x32_bf16(a0, b, acc[0][nt], 0, 0, 0);
                acc[1][nt] = __builtin_amdgcn_mfma_f32_16x16x32_bf16(a1, b, acc[1][nt], 0, 0, 0);
            }
        }
        __syncthreads();    // drains vmcnt(0): next buf staged; all reads of cur done
    }

#pragma unroll
    for (int nt = 0; nt < 4; ++nt) {
        int col = wv * 64 + nt * 16 + lo;
        float bias = sg.b[col];
#pragma unroll
        for (int mt = 0; mt < 2; ++mt)
#pragma unroll
            for (int r = 0; r < 4; ++r) {
                int row = m0 + mt * 16 + hi * 4 + r;
                sg.out[(size_t)row * E + col] = f2bf(acc[mt][nt][r] + bias);
            }
    }
}

// ---------- fused: sparse attn -> LDS -> outproj MFMA -> +resid -> LN (-> Q-next proj) ----------
// R8-verified structure (16 faces / 16 waves / 1024 thr -- R9 proved this is the
// efficient geometry). Single added lever, numerically bit-identical: V rows 0..7
// prefetched into registers right after lds_idx is written (T14 issue-early),
// overlapping half the V gather round with dedup+QK+softmax (~2000 cyc cover).
// +16 VGPR; __launch_bounds__(1024, 8) pins VGPR <= 64 so 2 blocks/CU survive.
// Accumulation order in the V phase is unchanged (j = 0..15 sequential).
__global__ __launch_bounds__(1024, 8) void attn_outproj_ln(
    const int* __restrict__ rel, const __hip_bfloat16* __restrict__ q16,
    const __hip_bfloat16* __restrict__ k16, const __hip_bfloat16* __restrict__ v16,
    const __hip_bfloat16* __restrict__ wout, const float* __restrict__ bout,
    const float* __restrict__ resid, const float* __restrict__ lng, const float* __restrict__ lnb,
    const __hip_bfloat16* __restrict__ wq_next, const float* __restrict__ bq_next,
    float* __restrict__ xres_out, __hip_bfloat16* __restrict__ qnext_out,
    float* __restrict__ final_out, int L, int ML)
{
    __shared__ __align__(16) __hip_bfloat16 atile[16 * 264];  // stride 264: 2-way banks (free)
    __shared__ __align__(16) float sm[16 * 260];
    __shared__ __align__(16) float lds_w[16][2][16];
    __shared__ int lds_idx[16][16];

    int tid = threadIdx.x, wv = tid >> 6, lane = tid & 63;
    int m0 = blockIdx.x * 16;
    int g = lane >> 2, q = lane & 3;
    int face = m0 + wv;
    const float scale = 0.088388347648318447f;  // 1/sqrt(128)

    // ---- hoisted cold reads: rel (gather indices) + resid row ----
    const int* rr = rel + (size_t)face * ML;
    int myidx = (g < ML) ? rr[g] : -1;
    float4 rv = *reinterpret_cast<const float4*>(resid + (size_t)face * E + 4 * lane);

    int safe = myidx < 0 ? 0 : myidx;
    if (q == 0) lds_idx[wv][g] = safe;     // intra-wave LDS ordering (base kernel
                                           // already relies on this for the V phase)

    // ---- early V prefetch, rows 0..7 (16 VGPR): overlaps dedup+QK+softmax ----
    short4v vr[8];
#pragma unroll
    for (int j = 0; j < 8; ++j)
        vr[j] = *reinterpret_cast<const short4v*>(v16 + (size_t)lds_idx[wv][j] * E + 4 * lane);

    bool dup = false;
#pragma unroll
    for (int d = 1; d < 16; ++d) {
        int other = __shfl(myidx, ((g - d) & 15) * 4 + q);
        if (d <= g && other == myidx) dup = true;
    }
    bool myuse = (myidx >= 0) && !dup;       // set semantics: unique valid edges

    // ---- QK dots (per-head, loads kept in-loop to cap liveness) ----
    float sc[2];
#pragma unroll
    for (int h = 0; h < 2; ++h) {
        const __hip_bfloat16* kbase = k16 + (size_t)safe * E + h * DH;
        const __hip_bfloat16* qbase = q16 + (size_t)face * E + h * DH;
        float part = 0.f;
#pragma unroll
        for (int t = 0; t < 4; ++t) {
            short8 qv = *reinterpret_cast<const short8*>(qbase + (t * 4 + q) * 8);
            short8 kv = *reinterpret_cast<const short8*>(kbase + (t * 4 + q) * 8);
            const __hip_bfloat16* qp = (const __hip_bfloat16*)&qv;
            const __hip_bfloat16* kp = (const __hip_bfloat16*)&kv;
#pragma unroll
            for (int e2 = 0; e2 < 8; ++e2)
                part += bf2f(qp[e2]) * bf2f(kp[e2]);
        }
        part += __shfl_xor(part, 1);
        part += __shfl_xor(part, 2);          // full 128-dim dot in all 4 quad lanes
        sc[h] = myuse ? part * scale : -1e30f;
    }
    // interleaved softmax reductions for both heads (2x ILP, identical values)
    {
        float mx0 = sc[0], mx1 = sc[1];
#pragma unroll
        for (int off = 4; off < 64; off <<= 1) {
            mx0 = fmaxf(mx0, __shfl_xor(mx0, off));
            mx1 = fmaxf(mx1, __shfl_xor(mx1, off));
        }
        float e0 = __expf(sc[0] - mx0), e1 = __expf(sc[1] - mx1);  // exactly 0 for dead slots
        float d0 = e0, d1 = e1;
#pragma unroll
        for (int off = 4; off < 64; off <<= 1) {
            d0 += __shfl_xor(d0, off);
            d1 += __shfl_xor(d1, off);
        }
        if (q == 0) { lds_w[wv][0][g] = e0 / d0; lds_w[wv][1][g] = e1 / d1; }
    }

    // V phase: lane covers dims [4*lane, 4*lane+4); j=0..7 from prefetched regs,
    // j=8..15 loaded here; accumulation order identical to the base kernel.
    {
        int h = lane >> 5;
        float a0 = 0.f, a1 = 0.f, a2 = 0.f, a3 = 0.f;
#pragma unroll
        for (int j = 0; j < 8; ++j) {
            float wj = lds_w[wv][h][j];       // 0 for unused edges
            const __hip_bfloat16* vp = (const __hip_bfloat16*)&vr[j];
            a0 += wj * bf2f(vp[0]);
            a1 += wj * bf2f(vp[1]);
            a2 += wj * bf2f(vp[2]);
            a3 += wj * bf2f(vp[3]);
        }
#pragma unroll
        for (int j = 8; j < 16; ++j) {
            int ij = lds_idx[wv][j];
            float wj = lds_w[wv][h][j];
            short4v vv = *reinterpret_cast<const short4v*>(v16 + (size_t)ij * E + 4 * lane);
            const __hip_bfloat16* vp = (const __hip_bfloat16*)&vv;
            a0 += wj * bf2f(vp[0]);
            a1 += wj * bf2f(vp[1]);
            a2 += wj * bf2f(vp[2]);
            a3 += wj * bf2f(vp[3]);
        }
        __hip_bfloat16 ob[4] = {f2bf(a0), f2bf(a1), f2bf(a2), f2bf(a3)};
        *reinterpret_cast<short4v*>(atile + wv * 264 + 4 * lane) =
            *reinterpret_cast<const short4v*>(ob);
    }
    __syncthreads();

    // ---- outproj MFMA: wave wv -> cols [wv*16, wv*16+16) ----
    {
        int lo = lane & 15, hi = lane >> 4;
        const __hip_bfloat16* arow = atile + lo * 264 + hi * 8;
        const __hip_bfloat16* brow = wout + (size_t)(wv * 16 + lo) * E + hi * 8;
        f32x4 acc = {0.f, 0.f, 0.f, 0.f};
#pragma unroll
        for (int kk = 0; kk < 8; ++kk) {
            short8 a = *reinterpret_cast<const short8*>(arow + kk * 32);
            short8 b = *reinterpret_cast<const short8*>(brow + kk * 32);
            acc = __builtin_amdgcn_mfma_f32_16x16x32_bf16(a, b, acc, 0, 0, 0);
        }
        int col = wv * 16 + lo;
#pragma unroll
        for (int r = 0; r < 4; ++r)
            sm[(hi * 4 + r) * 260 + col] = acc[r];
    }
    __syncthreads();

    // ---- LN: wave wv handles row wv; lane covers 4 cols (rv preloaded) ----
    {
        int rowg = m0 + wv;
        float4 pv = *reinterpret_cast<const float4*>(sm + wv * 260 + 4 * lane);
        float4 bb = *reinterpret_cast<const float4*>(bout + 4 * lane);
        float v0 = pv.x + bb.x + rv.x;
        float v1 = pv.y + bb.y + rv.y;
        float v2 = pv.z + bb.z + rv.z;
        float v3 = pv.w + bb.w + rv.w;
        float s  = v0 + v1 + v2 + v3;
        float s2 = v0 * v0 + v1 * v1 + v2 * v2 + v3 * v3;
#pragma unroll
        for (int off = 1; off < 64; off <<= 1) {
            s  += __shfl_xor(s, off);
            s2 += __shfl_xor(s2, off);
        }
        float mean = s * (1.f / 256.f);
        float var  = s2 * (1.f / 256.f) - mean * mean;
        float rstd = rsqrtf(var + 1e-5f);
        float4 gg = *reinterpret_cast<const float4*>(lng + 4 * lane);
        float4 b2 = *reinterpret_cast<const float4*>(lnb + 4 * lane);
        float y0 = (v0 - mean) * rstd * gg.x + b2.x;
        float y1 = (v1 - mean) * rstd * gg.y + b2.y;
        float y2 = (v2 - mean) * rstd * gg.z + b2.z;
        float y3 = (v3 - mean) * rstd * gg.w + b2.w;
        if (final_out) {
            float4 o = {y0, y1, y2, y3};
            *reinterpret_cast<float4*>(final_out + (size_t)rowg * E + 4 * lane) = o;  // fp32 d_out
        } else {
            float4 o = {y0, y1, y2, y3};
            *reinterpret_cast<float4*>(xres_out + (size_t)rowg * E + 4 * lane) = o;
            // stage LN output as bf16 for the fused Q-next projection
            __hip_bfloat16 ob[4] = {f2bf(y0), f2bf(y1), f2bf(y2), f2bf(y3)};
            *reinterpret_cast<short4v*>(atile + wv * 264 + 4 * lane) =
                *reinterpret_cast<const short4v*>(ob);
        }
    }

    // ---- fused Q-next projection (layer 0 only): q16[m0..m0+15] = y @ wq^T + bq ----
    if (qnext_out) {
        __syncthreads();   // atile(y) visible to all waves
        int lo = lane & 15, hi = lane >> 4;
        const __hip_bfloat16* arow = atile + lo * 264 + hi * 8;
        const __hip_bfloat16* brow = wq_next + (size_t)(wv * 16 + lo) * E + hi * 8;
        f32x4 acc = {0.f, 0.f, 0.f, 0.f};
#pragma unroll
        for (int kk = 0; kk < 8; ++kk) {
            short8 a = *reinterpret_cast<const short8*>(arow + kk * 32);
            short8 b = *reinterpret_cast<const short8*>(brow + kk * 32);
            acc = __builtin_amdgcn_mfma_f32_16x16x32_bf16(a, b, acc, 0, 0, 0);
        }
        int col = wv * 16 + lo;
        float bias = bq_next[col];
#pragma unroll
        for (int r = 0; r < 4; ++r)
            qnext_out[(size_t)(m0 + hi * 4 + r) * E + col] = f2bf(acc[r] + bias);
    }
}

extern "C" void kernel_launch(void* const* d_in, const int* in_sizes, int n_in,
                              void* d_out, int out_size, void* d_ws, size_t ws_size,
                              hipStream_t stream) {
    const int* rel = (const int*)d_in[0];
    const float* edge = (const float*)d_in[2];
    const float* face = (const float*)d_in[3];
    const float* w_in[2]  = {(const float*)d_in[4],  (const float*)d_in[10]};
    const float* b_in[2]  = {(const float*)d_in[5],  (const float*)d_in[11]};
    const float* w_out[2] = {(const float*)d_in[6],  (const float*)d_in[12]};
    const float* b_out[2] = {(const float*)d_in[7],  (const float*)d_in[13]};
    const float* ln_g[2]  = {(const float*)d_in[8],  (const float*)d_in[14]};
    const float* ln_b[2]  = {(const float*)d_in[9],  (const float*)d_in[15]};

    int S = in_sizes[2] / E;
    int L = in_sizes[3] / E;
    int ML = in_sizes[0] / L;

    char* ws = (char*)d_ws;
    __hip_bfloat16* face16 = (__hip_bfloat16*)ws; ws += (size_t)L * E * 2;
    __hip_bfloat16* edge16 = (__hip_bfloat16*)ws; ws += (size_t)S * E * 2;
    __hip_bfloat16* q16    = (__hip_bfloat16*)ws; ws += (size_t)L * E * 2;
    __hip_bfloat16* k16[2], *v16[2];
    for (int l = 0; l < 2; ++l) {
        k16[l] = (__hip_bfloat16*)ws; ws += (size_t)S * E * 2;
        v16[l] = (__hip_bfloat16*)ws; ws += (size_t)S * E * 2;
    }
    float* xres = (float*)ws;                     ws += (size_t)L * E * 4;
    __hip_bfloat16* win16[2], *wout16[2];
    for (int l = 0; l < 2; ++l) {
        win16[l]  = (__hip_bfloat16*)ws; ws += (size_t)3 * E * E * 2;
        wout16[l] = (__hip_bfloat16*)ws; ws += (size_t)E * E * 2;
    }

    float* outp = (float*)d_out;

    // 1) conversions (one launch)
    {
        CvtArgs ca;
        ca.in[0] = face;     ca.out[0] = face16;    ca.n[0] = L * E;
        ca.in[1] = edge;     ca.out[1] = edge16;    ca.n[1] = S * E;
        ca.in[2] = w_in[0];  ca.out[2] = win16[0];  ca.n[2] = 3 * E * E;
        ca.in[3] = w_in[1];  ca.out[3] = win16[1];  ca.n[3] = 3 * E * E;
        ca.in[4] = w_out[0]; ca.out[4] = wout16[0]; ca.n[4] = E * E;
        ca.in[5] = w_out[1]; ca.out[5] = wout16[1]; ca.n[5] = E * E;
        int gx = (L * E) / (256 * 8);
        f2b_all<<<dim3(gx, 6), 256, 0, stream>>>(ca);
    }

    // 2) Q0 + K0,V0,K1,V1 projections (one launch, 5 segments, LDS-staged)
    {
        ProjArgs pa;
        pa.seg[0] = {face16, win16[0],                     b_in[0],         q16};
        pa.seg[1] = {edge16, win16[0] + (size_t)E * E,     b_in[0] + E,     k16[0]};
        pa.seg[2] = {edge16, win16[0] + (size_t)2 * E * E, b_in[0] + 2 * E, v16[0]};
        pa.seg[3] = {edge16, win16[1] + (size_t)E * E,     b_in[1] + E,     k16[1]};
        pa.seg[4] = {edge16, win16[1] + (size_t)2 * E * E, b_in[1] + 2 * E, v16[1]};
        gemm_proj<<<dim3(L / 32, 5), 256, 0, stream>>>(pa, L);
    }

    // 3) layer 0: attn + outproj + LN + fused Q1 projection -> xres (f32) + q16 (bf16)
    attn_outproj_ln<<<L / 16, 1024, 0, stream>>>(rel, q16, k16[0], v16[0],
                                                 wout16[0], b_out[0], face,
                                                 ln_g[0], ln_b[0],
                                                 win16[1], b_in[1],
                                                 xres, q16, nullptr, L, ML);

    // 4) layer 1: attn + outproj + LN -> d_out (f32)
    attn_outproj_ln<<<L / 16, 1024, 0, stream>>>(rel, q16, k16[1], v16[1],
                                                 wout16[1], b_out[1], xres,
                                                 ln_g[1], ln_b[1],
                                                 nullptr, nullptr,
                                                 nullptr, nullptr, outp, L, ML);
}

// Round 11
// 166.788 us; speedup vs baseline: 1.1314x; 1.0717x over previous
//
#include <hip/hip_runtime.h>
#include <hip/hip_bf16.h>

typedef short short8 __attribute__((ext_vector_type(8)));
typedef short short4v __attribute__((ext_vector_type(4)));
typedef float f32x4 __attribute__((ext_vector_type(4)));

#define E 256
#define DH 128

__device__ __forceinline__ float bf2f(__hip_bfloat16 x) { return __bfloat162float(x); }
__device__ __forceinline__ __hip_bfloat16 f2bf(float x) { return __float2bfloat16(x); }

// ---------- fused fp32 -> bf16 convert for 6 arrays ----------
struct CvtArgs { const float* in[6]; __hip_bfloat16* out[6]; int n[6]; };

__global__ __launch_bounds__(256) void f2b_all(CvtArgs a)
{
    int seg = blockIdx.y;
    int i = (blockIdx.x * 256 + threadIdx.x) * 8;
    if (i >= a.n[seg]) return;
    const float* in = a.in[seg];
    float4 x = *reinterpret_cast<const float4*>(in + i);
    float4 y = *reinterpret_cast<const float4*>(in + i + 4);
    __hip_bfloat16* o = a.out[seg] + i;
    o[0] = f2bf(x.x); o[1] = f2bf(x.y); o[2] = f2bf(x.z); o[3] = f2bf(x.w);
    o[4] = f2bf(y.x); o[5] = f2bf(y.y); o[6] = f2bf(y.z); o[7] = f2bf(y.w);
}

// ---------- projection GEMM: out[M,256] = A[M,256] @ W[256,256]^T + b ----------
// LDS-staged 2-phase pipeline (global_load_lds width=16): DMA-queued staging at
// zero VGPR cost (the R5 win: 179->169); W-slab shared per block; XOR swizzle
// applied both-sides (pre-swizzled source + swizzled read).
struct ProjSeg { const __hip_bfloat16* A; const __hip_bfloat16* W; const float* b; __hip_bfloat16* out; };
struct ProjArgs { ProjSeg seg[5]; };

#define GLDS(g, l) __builtin_amdgcn_global_load_lds( \
    (const __attribute__((address_space(1))) void*)(g), \
    (__attribute__((address_space(3))) void*)(l), 16, 0, 0)

__global__ __launch_bounds__(256) void gemm_proj(ProjArgs args, int M)
{
    __shared__ __hip_bfloat16 sA[2][32 * 64];    //  8 KB: A slab, 32 rows x 64 k
    __shared__ __hip_bfloat16 sW[2][256 * 64];   // 64 KB: W slab, 256 rows x 64 k

    int wv = threadIdx.x >> 6, lane = threadIdx.x & 63;
    int m0 = blockIdx.x * 32;
    ProjSeg sg = args.seg[blockIdx.y];
    int lo = lane & 15, hi = lane >> 4;

    int lr = lane >> 3;                        // row within 8-row group == row&7
    int lcol = ((lane & 7) ^ lr) * 8;          // pre-swizzled source col (elements)

    auto stage = [&](int buf, int kc) {
        {   // A: instr index = wv, rows wv*8 .. wv*8+8
            int R = wv * 8 + lr;
            GLDS(sg.A + (size_t)(m0 + R) * E + kc * 64 + lcol, &sA[buf][(wv * 8) * 64]);
        }
#pragma unroll
        for (int s = 0; s < 8; ++s) {   // W: instrs wv*8+s, rows wv*64+s*8 ..+8
            int R = wv * 64 + s * 8 + lr;
            GLDS(sg.W + (size_t)R * E + kc * 64 + lcol, &sW[buf][(wv * 64 + s * 8) * 64]);
        }
    };

    stage(0, 0);
    __syncthreads();                            // drain vmcnt(0): buf0 ready

    f32x4 acc[2][4] = {};
    const int swz = (lo & 7);                   // read-side swizzle term (row&7)
#pragma unroll
    for (int kc = 0; kc < 4; ++kc) {
        int cur = kc & 1;
        if (kc < 3) stage(cur ^ 1, kc + 1);     // DMA flies under this chunk's math

        const char* aB = (const char*)sA[cur];
        const char* wB = (const char*)sW[cur];
#pragma unroll
        for (int ks = 0; ks < 2; ++ks) {
            int phys = ((hi + 4 * ks) ^ swz) * 16;   // swizzled 16B slot in row
            short8 a0 = *reinterpret_cast<const short8*>(aB + (0 * 16 + lo) * 128 + phys);
            short8 a1 = *reinterpret_cast<const short8*>(aB + (1 * 16 + lo) * 128 + phys);
#pragma unroll
            for (int nt = 0; nt < 4; ++nt) {
                short8 b = *reinterpret_cast<const short8*>(
                    wB + (wv * 64 + nt * 16 + lo) * 128 + phys);
                acc[0][nt] = __builtin_amdgcn_mfma_f32_16x16x32_bf16(a0, b, acc[0][nt], 0, 0, 0);
                acc[1][nt] = __builtin_amdgcn_mfma_f32_16x16x32_bf16(a1, b, acc[1][nt], 0, 0, 0);
            }
        }
        __syncthreads();    // drains vmcnt(0): next buf staged; all reads of cur done
    }

#pragma unroll
    for (int nt = 0; nt < 4; ++nt) {
        int col = wv * 64 + nt * 16 + lo;
        float bias = sg.b[col];
#pragma unroll
        for (int mt = 0; mt < 2; ++mt)
#pragma unroll
            for (int r = 0; r < 4; ++r) {
                int row = m0 + mt * 16 + hi * 4 + r;
                sg.out[(size_t)row * E + col] = f2bf(acc[mt][nt][r] + bias);
            }
    }
}

// ---------- fused: sparse attn -> LDS -> outproj MFMA -> +resid -> LN (-> Q-next proj) ----------
// Best-verified configuration (R5, 169.0 us). 16 faces / 16 waves / 1024 thr;
// R9 proved this geometry is the efficient point (8-wave blocks doubled per-face
// MFMA work); R3/R10 proved register prefetch hoists cost occupancy/spills.
__global__ __launch_bounds__(1024) void attn_outproj_ln(
    const int* __restrict__ rel, const __hip_bfloat16* __restrict__ q16,
    const __hip_bfloat16* __restrict__ k16, const __hip_bfloat16* __restrict__ v16,
    const __hip_bfloat16* __restrict__ wout, const float* __restrict__ bout,
    const float* __restrict__ resid, const float* __restrict__ lng, const float* __restrict__ lnb,
    const __hip_bfloat16* __restrict__ wq_next, const float* __restrict__ bq_next,
    float* __restrict__ xres_out, __hip_bfloat16* __restrict__ qnext_out,
    float* __restrict__ final_out, int L, int ML)
{
    __shared__ __align__(16) __hip_bfloat16 atile[16 * 264];  // stride 264: 2-way banks (free)
    __shared__ __align__(16) float sm[16 * 260];
    __shared__ __align__(16) float lds_w[16][2][16];
    __shared__ int lds_idx[16][16];

    int tid = threadIdx.x, wv = tid >> 6, lane = tid & 63;
    int m0 = blockIdx.x * 16;
    int g = lane >> 2, q = lane & 3;
    int face = m0 + wv;
    const float scale = 0.088388347648318447f;  // 1/sqrt(128)

    // ---- attention: one face per wave ----
    const int* rr = rel + (size_t)face * ML;
    int myidx = (g < ML) ? rr[g] : -1;

    bool dup = false;
#pragma unroll
    for (int d = 1; d < 16; ++d) {
        int other = __shfl(myidx, ((g - d) & 15) * 4 + q);
        if (d <= g && other == myidx) dup = true;
    }
    bool myuse = (myidx >= 0) && !dup;       // set semantics: unique valid edges
    int safe = myidx < 0 ? 0 : myidx;
    if (q == 0) lds_idx[wv][g] = safe;

#pragma unroll
    for (int h = 0; h < 2; ++h) {
        const __hip_bfloat16* kbase = k16 + (size_t)safe * E + h * DH;
        const __hip_bfloat16* qbase = q16 + (size_t)face * E + h * DH;
        float part = 0.f;
#pragma unroll
        for (int t = 0; t < 4; ++t) {
            short8 qv = *reinterpret_cast<const short8*>(qbase + (t * 4 + q) * 8);
            short8 kv = *reinterpret_cast<const short8*>(kbase + (t * 4 + q) * 8);
            const __hip_bfloat16* qp = (const __hip_bfloat16*)&qv;
            const __hip_bfloat16* kp = (const __hip_bfloat16*)&kv;
#pragma unroll
            for (int e2 = 0; e2 < 8; ++e2)
                part += bf2f(qp[e2]) * bf2f(kp[e2]);
        }
        part += __shfl_xor(part, 1);
        part += __shfl_xor(part, 2);          // full 128-dim dot in all 4 quad lanes
        float sc = myuse ? part * scale : -1e30f;
        float mx = sc;
#pragma unroll
        for (int off = 4; off < 64; off <<= 1) mx = fmaxf(mx, __shfl_xor(mx, off));
        float e = __expf(sc - mx);            // exactly 0 for dead slots
        float den = e;
#pragma unroll
        for (int off = 4; off < 64; off <<= 1) den += __shfl_xor(den, off);
        if (q == 0) lds_w[wv][h][g] = e / den;
    }

    // V phase: lane covers dims [4*lane, 4*lane+4) of the 256-dim row
    {
        int h = lane >> 5;
        float a0 = 0.f, a1 = 0.f, a2 = 0.f, a3 = 0.f;
#pragma unroll
        for (int j = 0; j < 16; ++j) {
            int ij = lds_idx[wv][j];
            float wj = lds_w[wv][h][j];       // 0 for unused edges
            short4v vv = *reinterpret_cast<const short4v*>(v16 + (size_t)ij * E + 4 * lane);
            const __hip_bfloat16* vp = (const __hip_bfloat16*)&vv;
            a0 += wj * bf2f(vp[0]);
            a1 += wj * bf2f(vp[1]);
            a2 += wj * bf2f(vp[2]);
            a3 += wj * bf2f(vp[3]);
        }
        __hip_bfloat16 ob[4] = {f2bf(a0), f2bf(a1), f2bf(a2), f2bf(a3)};
        *reinterpret_cast<short4v*>(atile + wv * 264 + 4 * lane) =
            *reinterpret_cast<const short4v*>(ob);
    }
    __syncthreads();

    // ---- outproj MFMA: wave wv -> cols [wv*16, wv*16+16) ----
    {
        int lo = lane & 15, hi = lane >> 4;
        const __hip_bfloat16* arow = atile + lo * 264 + hi * 8;
        const __hip_bfloat16* brow = wout + (size_t)(wv * 16 + lo) * E + hi * 8;
        f32x4 acc = {0.f, 0.f, 0.f, 0.f};
#pragma unroll
        for (int kk = 0; kk < 8; ++kk) {
            short8 a = *reinterpret_cast<const short8*>(arow + kk * 32);
            short8 b = *reinterpret_cast<const short8*>(brow + kk * 32);
            acc = __builtin_amdgcn_mfma_f32_16x16x32_bf16(a, b, acc, 0, 0, 0);
        }
        int col = wv * 16 + lo;
#pragma unroll
        for (int r = 0; r < 4; ++r)
            sm[(hi * 4 + r) * 260 + col] = acc[r];
    }
    __syncthreads();

    // ---- LN: wave wv handles row wv; lane covers 4 cols ----
    {
        int rowg = m0 + wv;
        float4 pv = *reinterpret_cast<const float4*>(sm + wv * 260 + 4 * lane);
        float4 rv = *reinterpret_cast<const float4*>(resid + (size_t)rowg * E + 4 * lane);
        float4 bb = *reinterpret_cast<const float4*>(bout + 4 * lane);
        float v0 = pv.x + bb.x + rv.x;
        float v1 = pv.y + bb.y + rv.y;
        float v2 = pv.z + bb.z + rv.z;
        float v3 = pv.w + bb.w + rv.w;
        float s  = v0 + v1 + v2 + v3;
        float s2 = v0 * v0 + v1 * v1 + v2 * v2 + v3 * v3;
#pragma unroll
        for (int off = 1; off < 64; off <<= 1) {
            s  += __shfl_xor(s, off);
            s2 += __shfl_xor(s2, off);
        }
        float mean = s * (1.f / 256.f);
        float var  = s2 * (1.f / 256.f) - mean * mean;
        float rstd = rsqrtf(var + 1e-5f);
        float4 gg = *reinterpret_cast<const float4*>(lng + 4 * lane);
        float4 b2 = *reinterpret_cast<const float4*>(lnb + 4 * lane);
        float y0 = (v0 - mean) * rstd * gg.x + b2.x;
        float y1 = (v1 - mean) * rstd * gg.y + b2.y;
        float y2 = (v2 - mean) * rstd * gg.z + b2.z;
        float y3 = (v3 - mean) * rstd * gg.w + b2.w;
        if (final_out) {
            float4 o = {y0, y1, y2, y3};
            *reinterpret_cast<float4*>(final_out + (size_t)rowg * E + 4 * lane) = o;  // fp32 d_out
        } else {
            float4 o = {y0, y1, y2, y3};
            *reinterpret_cast<float4*>(xres_out + (size_t)rowg * E + 4 * lane) = o;
            // stage LN output as bf16 for the fused Q-next projection
            __hip_bfloat16 ob[4] = {f2bf(y0), f2bf(y1), f2bf(y2), f2bf(y3)};
            *reinterpret_cast<short4v*>(atile + wv * 264 + 4 * lane) =
                *reinterpret_cast<const short4v*>(ob);
        }
    }

    // ---- fused Q-next projection (layer 0 only): q16[m0..m0+15] = y @ wq^T + bq ----
    if (qnext_out) {
        __syncthreads();   // atile(y) visible to all waves
        int lo = lane & 15, hi = lane >> 4;
        const __hip_bfloat16* arow = atile + lo * 264 + hi * 8;
        const __hip_bfloat16* brow = wq_next + (size_t)(wv * 16 + lo) * E + hi * 8;
        f32x4 acc = {0.f, 0.f, 0.f, 0.f};
#pragma unroll
        for (int kk = 0; kk < 8; ++kk) {
            short8 a = *reinterpret_cast<const short8*>(arow + kk * 32);
            short8 b = *reinterpret_cast<const short8*>(brow + kk * 32);
            acc = __builtin_amdgcn_mfma_f32_16x16x32_bf16(a, b, acc, 0, 0, 0);
        }
        int col = wv * 16 + lo;
        float bias = bq_next[col];
#pragma unroll
        for (int r = 0; r < 4; ++r)
            qnext_out[(size_t)(m0 + hi * 4 + r) * E + col] = f2bf(acc[r] + bias);
    }
}

extern "C" void kernel_launch(void* const* d_in, const int* in_sizes, int n_in,
                              void* d_out, int out_size, void* d_ws, size_t ws_size,
                              hipStream_t stream) {
    const int* rel = (const int*)d_in[0];
    const float* edge = (const float*)d_in[2];
    const float* face = (const float*)d_in[3];
    const float* w_in[2]  = {(const float*)d_in[4],  (const float*)d_in[10]};
    const float* b_in[2]  = {(const float*)d_in[5],  (const float*)d_in[11]};
    const float* w_out[2] = {(const float*)d_in[6],  (const float*)d_in[12]};
    const float* b_out[2] = {(const float*)d_in[7],  (const float*)d_in[13]};
    const float* ln_g[2]  = {(const float*)d_in[8],  (const float*)d_in[14]};
    const float* ln_b[2]  = {(const float*)d_in[9],  (const float*)d_in[15]};

    int S = in_sizes[2] / E;
    int L = in_sizes[3] / E;
    int ML = in_sizes[0] / L;

    char* ws = (char*)d_ws;
    __hip_bfloat16* face16 = (__hip_bfloat16*)ws; ws += (size_t)L * E * 2;
    __hip_bfloat16* edge16 = (__hip_bfloat16*)ws; ws += (size_t)S * E * 2;
    __hip_bfloat16* q16    = (__hip_bfloat16*)ws; ws += (size_t)L * E * 2;
    __hip_bfloat16* k16[2], *v16[2];
    for (int l = 0; l < 2; ++l) {
        k16[l] = (__hip_bfloat16*)ws; ws += (size_t)S * E * 2;
        v16[l] = (__hip_bfloat16*)ws; ws += (size_t)S * E * 2;
    }
    float* xres = (float*)ws;                     ws += (size_t)L * E * 4;
    __hip_bfloat16* win16[2], *wout16[2];
    for (int l = 0; l < 2; ++l) {
        win16[l]  = (__hip_bfloat16*)ws; ws += (size_t)3 * E * E * 2;
        wout16[l] = (__hip_bfloat16*)ws; ws += (size_t)E * E * 2;
    }

    float* outp = (float*)d_out;

    // 1) conversions (one launch)
    {
        CvtArgs ca;
        ca.in[0] = face;     ca.out[0] = face16;    ca.n[0] = L * E;
        ca.in[1] = edge;     ca.out[1] = edge16;    ca.n[1] = S * E;
        ca.in[2] = w_in[0];  ca.out[2] = win16[0];  ca.n[2] = 3 * E * E;
        ca.in[3] = w_in[1];  ca.out[3] = win16[1];  ca.n[3] = 3 * E * E;
        ca.in[4] = w_out[0]; ca.out[4] = wout16[0]; ca.n[4] = E * E;
        ca.in[5] = w_out[1]; ca.out[5] = wout16[1]; ca.n[5] = E * E;
        int gx = (L * E) / (256 * 8);
        f2b_all<<<dim3(gx, 6), 256, 0, stream>>>(ca);
    }

    // 2) Q0 + K0,V0,K1,V1 projections (one launch, 5 segments, LDS-staged)
    {
        ProjArgs pa;
        pa.seg[0] = {face16, win16[0],                     b_in[0],         q16};
        pa.seg[1] = {edge16, win16[0] + (size_t)E * E,     b_in[0] + E,     k16[0]};
        pa.seg[2] = {edge16, win16[0] + (size_t)2 * E * E, b_in[0] + 2 * E, v16[0]};
        pa.seg[3] = {edge16, win16[1] + (size_t)E * E,     b_in[1] + E,     k16[1]};
        pa.seg[4] = {edge16, win16[1] + (size_t)2 * E * E, b_in[1] + 2 * E, v16[1]};
        gemm_proj<<<dim3(L / 32, 5), 256, 0, stream>>>(pa, L);
    }

    // 3) layer 0: attn + outproj + LN + fused Q1 projection -> xres (f32) + q16 (bf16)
    attn_outproj_ln<<<L / 16, 1024, 0, stream>>>(rel, q16, k16[0], v16[0],
                                                 wout16[0], b_out[0], face,
                                                 ln_g[0], ln_b[0],
                                                 win16[1], b_in[1],
                                                 xres, q16, nullptr, L, ML);

    // 4) layer 1: attn + outproj + LN -> d_out (f32)
    attn_outproj_ln<<<L / 16, 1024, 0, stream>>>(rel, q16, k16[1], v16[1],
                                                 wout16[1], b_out[1], xres,
                                                 ln_g[1], ln_b[1],
                                                 nullptr, nullptr,
                                                 nullptr, nullptr, outp, L, ML);
}